// Round 9
// baseline (804.750 us; speedup 1.0000x reference)
//
#include <hip/hip_runtime.h>

// ---------------------------------------------------------------------------
// AdderNet 6-layer stack on MI355X (gfx950).
// out[n,o,p] = -sum_k |patch[p,k] - w[o,k]|
//
// R8: v_sad_u32 fixed-point -> 672us. R10: 64x128 4x8 micro -> 669us (wash:
//     L2 314->~308 but L1 regressed to ~308 when its grid halved).
//     Issue-accounting: 4x8 = 3 ds_read_b128 / 32 upd -> LDS-issue-bound
//     2.25x over VALU; L1 idle (28% LDS util) at 24% occupancy.
// R12: ONE change: 8x8 micro on 128x128 tile, two-halves layout (pixels
//     {tx*4, 64+tx*4}, och {ty*4, 64+ty*4}) = 4 ds_read_b128 / 64 upd:
//     LDS-issue/update x1.5 better, 1.0 B/update, 64 indep sad chains.
//     Bank patterns structurally identical to R10's measured-0-conflict ones.
//     Staging/BNQ/prefetch/combine = R10 verbatim. launch_bounds(256,3).
// ---------------------------------------------------------------------------

#define QSCALE 131072.0f            /* 2^17 */
#define QBIAS  1048576.5f           /* 2^20 + 0.5 (round via trunc) */
#define QINV   7.62939453125e-06    /* 2^-17 */

template <bool IS3x3, bool BN>
__global__ __launch_bounds__(256, 3)
void adder_conv(const float* __restrict__ x, const unsigned* __restrict__ wT,
                const float2* __restrict__ ab, unsigned* __restrict__ part,
                int Cin, int H, int W, int Wo, int Cout,
                int stride, int pad, int cpz, int P, int PI, int Pp)
{
    constexpr int KC = 32;
    __shared__ unsigned xs[KC][132]; // 128 pix + 4 pad (R10's 64+4 mirrored)
    __shared__ unsigned ws[KC][128]; // 128 och (R10 layout verbatim)
    __shared__ float2 abls[512];

    const int t  = threadIdx.x;
    const int tx = t & 15, ty = t >> 4;          // compute: 8 pix x 8 och (2x2 halves)
    const int ptile = blockIdx.x * 128, otile = blockIdx.y * 128;
    const int pp = t & 127, rg = t >> 7;         // xs staging: pixel, k-group (0/1)
    const int oq = t & 31, kr = t >> 5;          // ws staging: och-quad, k-row

    if (BN) {
        for (int i = t; i < Cin; i += 256) abls[i] = ab[i];
        __syncthreads();
    }

    // staging pixel decode (fixed per thread)
    const int p_st = ptile + pp;
    const bool pv = p_st < P;
    int n_st = 0, q = 0;
    if (pv) { n_st = p_st / PI; q = p_st - n_st * PI; }
    const int oh = q / Wo, ow = q - oh * Wo;
    const int ih0 = oh * stride - pad, iw0 = ow * stride - pad;
    const int HWi = H * W;
    const float* xb = x + (size_t)n_st * Cin * HWi;
    const unsigned* wbase = wT + otile + oq * 4;

    unsigned acc[2][4][8] = {};   // [pix-half][pix-in-quad][och: 0-3 lo, 4-7 hi]

    const int chunkBeg = blockIdx.z * cpz, chunkEnd = chunkBeg + cpz;

    // ---- prefetch state: NAMED scalars only (16 x rows of 2-stride, 4 w rows)
    float xr0, xr1, xr2, xr3, xr4, xr5, xr6, xr7;
    float xr8, xr9, xr10, xr11, xr12, xr13, xr14, xr15;
    uint4 wr0, wr1, wr2, wr3;
    int c0P = 0; bool vP = false;

#define ISSUE(CH) do {                                                        \
        const int k0_ = (CH) * KC;                                            \
        int c0_, ih_, iw_;                                                    \
        if (IS3x3) {                                                          \
            const int tap_ = k0_ / Cin;          /* uniform per chunk */      \
            c0_ = k0_ - tap_ * Cin;                                           \
            const int kh_ = tap_ / 3, kw_ = tap_ - kh_ * 3;                   \
            ih_ = ih0 + kh_; iw_ = iw0 + kw_;                                 \
        } else { c0_ = k0_; ih_ = ih0; iw_ = iw0; }                           \
        vP = pv && (!IS3x3 || (ih_ >= 0 && ih_ < H && iw_ >= 0 && iw_ < W));  \
        c0P = c0_;                                                            \
        const float* px_ = xb + (size_t)(c0_ + rg) * HWi + (ih_ * W + iw_);   \
        xr0  = vP ? px_[0] : 0.f;                                             \
        xr1  = vP ? px_[(size_t) 2 * HWi] : 0.f;                              \
        xr2  = vP ? px_[(size_t) 4 * HWi] : 0.f;                              \
        xr3  = vP ? px_[(size_t) 6 * HWi] : 0.f;                              \
        xr4  = vP ? px_[(size_t) 8 * HWi] : 0.f;                              \
        xr5  = vP ? px_[(size_t)10 * HWi] : 0.f;                              \
        xr6  = vP ? px_[(size_t)12 * HWi] : 0.f;                              \
        xr7  = vP ? px_[(size_t)14 * HWi] : 0.f;                              \
        xr8  = vP ? px_[(size_t)16 * HWi] : 0.f;                              \
        xr9  = vP ? px_[(size_t)18 * HWi] : 0.f;                              \
        xr10 = vP ? px_[(size_t)20 * HWi] : 0.f;                              \
        xr11 = vP ? px_[(size_t)22 * HWi] : 0.f;                              \
        xr12 = vP ? px_[(size_t)24 * HWi] : 0.f;                              \
        xr13 = vP ? px_[(size_t)26 * HWi] : 0.f;                              \
        xr14 = vP ? px_[(size_t)28 * HWi] : 0.f;                              \
        xr15 = vP ? px_[(size_t)30 * HWi] : 0.f;                              \
        const unsigned* pw_ = wbase + (size_t)(k0_ + kr) * Cout;              \
        wr0 = *(const uint4*)(pw_);                                           \
        wr1 = *(const uint4*)(pw_ + (size_t) 8 * Cout);                       \
        wr2 = *(const uint4*)(pw_ + (size_t)16 * Cout);                       \
        wr3 = *(const uint4*)(pw_ + (size_t)24 * Cout);                       \
    } while (0)

    // BN (optional) then quantize: u = trunc(v*2^17 + 2^20 + 0.5)
#define BNQ(V, J, DST)                                                        \
        {                                                                     \
            float vv_ = V;                                                    \
            if (BN) {                                                         \
                const float2 s_ = abls[c0P + rg + 2 * (J)];                   \
                vv_ = fminf(fmaxf(fmaf(s_.x, vv_, s_.y), 0.f), 6.f);          \
                vv_ = vP ? vv_ : 0.f;      /* padding stays literal 0 */      \
            }                                                                 \
            DST = (unsigned)fmaf(vv_, QSCALE, QBIAS);                         \
        }

#define WRITE_LDS() do {                                                      \
        unsigned q0_, q1_, q2_, q3_, q4_, q5_, q6_, q7_;                      \
        unsigned q8_, q9_, qA_, qB_, qC_, qD_, qE_, qF_;                      \
        BNQ(xr0,  0, q0_) BNQ(xr1,  1, q1_) BNQ(xr2,  2, q2_) BNQ(xr3,  3, q3_) \
        BNQ(xr4,  4, q4_) BNQ(xr5,  5, q5_) BNQ(xr6,  6, q6_) BNQ(xr7,  7, q7_) \
        BNQ(xr8,  8, q8_) BNQ(xr9,  9, q9_) BNQ(xr10,10, qA_) BNQ(xr11,11, qB_) \
        BNQ(xr12,12, qC_) BNQ(xr13,13, qD_) BNQ(xr14,14, qE_) BNQ(xr15,15, qF_) \
        xs[rg     ][pp] = q0_; xs[rg +  2][pp] = q1_;                         \
        xs[rg +  4][pp] = q2_; xs[rg +  6][pp] = q3_;                         \
        xs[rg +  8][pp] = q4_; xs[rg + 10][pp] = q5_;                         \
        xs[rg + 12][pp] = q6_; xs[rg + 14][pp] = q7_;                         \
        xs[rg + 16][pp] = q8_; xs[rg + 18][pp] = q9_;                         \
        xs[rg + 20][pp] = qA_; xs[rg + 22][pp] = qB_;                         \
        xs[rg + 24][pp] = qC_; xs[rg + 26][pp] = qD_;                         \
        xs[rg + 28][pp] = qE_; xs[rg + 30][pp] = qF_;                         \
        *(uint4*)&ws[kr     ][oq * 4] = wr0;                                  \
        *(uint4*)&ws[kr +  8][oq * 4] = wr1;                                  \
        *(uint4*)&ws[kr + 16][oq * 4] = wr2;                                  \
        *(uint4*)&ws[kr + 24][oq * 4] = wr3;                                  \
    } while (0)

    ISSUE(chunkBeg);

    for (int ch = chunkBeg; ch < chunkEnd; ++ch) {
        // [A] regs -> LDS (BN + quantize fused)
        WRITE_LDS();
        // [B] issue next chunk's global loads (vmcnt never drained in-loop)
        if (ch + 1 < chunkEnd) ISSUE(ch + 1);
        // [C] only the LDS writes must be visible before the barrier
        asm volatile("s_waitcnt lgkmcnt(0)" ::: "memory");
        __builtin_amdgcn_s_barrier();
        asm volatile("" ::: "memory");

        // ---- inner: 4 ds_read_b128 + 64 v_sad_u32 per kk
#pragma unroll 2
        for (int kk = 0; kk < KC; ++kk) {
            const uint4 xa = *(const uint4*)&xs[kk][tx * 4];
            const uint4 xb2 = *(const uint4*)&xs[kk][64 + tx * 4];
            const uint4 wa = *(const uint4*)&ws[kk][ty * 4];
            const uint4 wb = *(const uint4*)&ws[kk][64 + ty * 4];
#define S1(A, XC, WC) asm("v_sad_u32 %0, %1, %2, %0" : "+v"(A) : "v"(XC), "v"(WC));
#define SROW(a, i, XC)                                            \
            S1(acc[a][i][0], XC, wa.x) S1(acc[a][i][1], XC, wa.y) \
            S1(acc[a][i][2], XC, wa.z) S1(acc[a][i][3], XC, wa.w) \
            S1(acc[a][i][4], XC, wb.x) S1(acc[a][i][5], XC, wb.y) \
            S1(acc[a][i][6], XC, wb.z) S1(acc[a][i][7], XC, wb.w)
            SROW(0, 0, xa.x) SROW(0, 1, xa.y) SROW(0, 2, xa.z) SROW(0, 3, xa.w)
            SROW(1, 0, xb2.x) SROW(1, 1, xb2.y) SROW(1, 2, xb2.z) SROW(1, 3, xb2.w)
#undef SROW
#undef S1
        }
        asm volatile("" ::: "memory");
        __builtin_amdgcn_s_barrier();
        asm volatile("" ::: "memory");
    }
#undef ISSUE
#undef BNQ
#undef WRITE_LDS

    // ---- plain coalesced stores into this z-slice's partial buffer
#pragma unroll
    for (int a = 0; a < 2; ++a) {
        const int p0 = ptile + a * 64 + tx * 4;
        const bool full = (p0 + 3) < P;
#pragma unroll
        for (int jj = 0; jj < 8; ++jj) {
            const int o = otile + (jj < 4 ? ty * 4 + jj : 64 + ty * 4 + (jj - 4));
            unsigned* dst = part + ((size_t)blockIdx.z * Cout + o) * Pp + p0;
            if (full) {
                *(uint4*)dst = make_uint4(acc[a][0][jj], acc[a][1][jj],
                                          acc[a][2][jj], acc[a][3][jj]);
            } else {
#pragma unroll
                for (int i = 0; i < 4; ++i)
                    if (p0 + i < P) dst[i] = acc[a][i][jj];
            }
        }
    }
}

// fused: sum Z u32 partial slices, rescale + negate -> float [n][c][PI], and
// accumulate per-channel sum/sumsq (double) for BN stats.
__global__ void combine_stats(const unsigned* __restrict__ part, float* __restrict__ fin,
                              double* __restrict__ st, int C, int PI, int Z, int Pp)
{
    const int c = blockIdx.x, n = blockIdx.y, t = threadIdx.x;
    const int pbase = n * PI;
    double s = 0.0, s2 = 0.0;
    for (int qq = t; qq < PI; qq += 256) {
        unsigned long long u = 0;
        for (int z = 0; z < Z; ++z)
            u += part[((size_t)z * C + c) * Pp + pbase + qq];
        const float v = -(float)((double)u * QINV);
        fin[((size_t)n * C + c) * PI + qq] = v;
        s += v; s2 += (double)v * v;
    }
    __shared__ double sh[256], sh2[256];
    sh[t] = s; sh2[t] = s2; __syncthreads();
    for (int off = 128; off > 0; off >>= 1) {
        if (t < off) { sh[t] += sh[t + off]; sh2[t] += sh2[t + off]; }
        __syncthreads();
    }
    if (t == 0) {
        unsafeAtomicAdd(&st[2 * c], sh[0]);
        unsafeAtomicAdd(&st[2 * c + 1], sh2[0]);
    }
}

// per-channel affine fold: a = g*rsqrt(var+eps), b = beta - mean*a
__global__ void ab_kernel(const double* __restrict__ st, const float* __restrict__ gamma,
                          const float* __restrict__ beta, float2* __restrict__ ab,
                          int C, double invCount)
{
    const int c = blockIdx.x * blockDim.x + threadIdx.x;
    if (c < C) {
        const double mean = st[2 * c] * invCount;
        const double var  = st[2 * c + 1] * invCount - mean * mean;
        const float a = gamma[c] * rsqrtf((float)var + 1e-5f);
        const float b = beta[c] - (float)mean * a;
        ab[c] = make_float2(a, b);
    }
}

// final BN+ReLU6 -> d_out
__global__ void apply_kernel(const float* __restrict__ y, const float2* __restrict__ ab,
                             float* __restrict__ out, int total, int C, int PI)
{
    const int i = blockIdx.x * 256 + threadIdx.x;
    if (i < total) {
        const int c = (i / PI) % C;
        const float2 s = ab[c];
        out[i] = fminf(fmaxf(fmaf(s.x, y[i], s.y), 0.f), 6.f);
    }
}

// merged weight transposes + fixed-point quantize:
// w [Cout][Cin][tap] -> wT [tap*Cin + c][Cout], u32 = round(w*2^17) + 2^20
struct TDesc { const float* w; unsigned* wT; int Cout; int Cin; int Tap; int elems; };
struct TPack { TDesc d[6]; };

__global__ void transpose_all(TPack p)
{
    const TDesc d = p.d[blockIdx.y];
    const int i = blockIdx.x * 256 + threadIdx.x;
    if (i < d.elems) {
        const int k = i / d.Cout, o = i - k * d.Cout;
        const int tap = k / d.Cin, c = k - tap * d.Cin;
        const float v = d.w[((size_t)o * d.Cin + c) * d.Tap + tap];
        d.wT[i] = (unsigned)fmaf(v, QSCALE, QBIAS);
    }
}

extern "C" void kernel_launch(void* const* d_in, const int* in_sizes, int n_in,
                              void* d_out, int out_size, void* d_ws, size_t ws_size,
                              hipStream_t stream)
{
    const float* x = (const float*)d_in[0];
    const float *w[6], *g[6], *bt[6];
    for (int i = 0; i < 6; ++i) {
        w[i]  = (const float*)d_in[1 + 3 * i];
        g[i]  = (const float*)d_in[2 + 3 * i];
        bt[i] = (const float*)d_in[3 + 3 * i];
    }

    char* ws = (char*)d_ws;
    float* bufA = (float*)ws;                                   // 23,658,496 B
    float* bufB = (float*)(ws + 23658496);                      // 11,829,248 B
    unsigned* part = (unsigned*)(ws + 23658496 + 11829248);     // 23,658,496 B
    size_t off = 23658496 + 11829248 + 23658496;
    const int wElems[6] = {256 * 512, 512 * 2304, 128 * 512,
                           256 * 1152, 128 * 256, 256 * 1152};
    unsigned* wT[6];
    for (int i = 0; i < 6; ++i) { wT[i] = (unsigned*)(ws + off); off += (size_t)wElems[i] * 4; }
    double* st = (double*)(ws + off); off += 3072 * 8;
    float2* ab = (float2*)(ws + off);
    const int stOff[6] = {0, 512, 1536, 1792, 2304, 2560};
    const int abOff[6] = {0, 256, 768, 896, 1152, 1280};

    const dim3 blk(256);

    // zero stats accumulators (ws is poisoned 0xAA before every launch)
    hipMemsetAsync(st, 0, 3072 * 8, stream);

    // merged weight transposes (tap-major k order) + quantize
    TPack tp;
    const int wCout[6] = {256, 512, 128, 256, 128, 256};
    const int wCin[6]  = {512, 256, 512, 128, 256, 128};
    const int wTap[6]  = {1, 9, 1, 9, 1, 9};
    for (int i = 0; i < 6; ++i)
        tp.d[i] = TDesc{w[i], wT[i], wCout[i], wCin[i], wTap[i], wElems[i]};
    transpose_all<<<dim3((1179648 + 255) / 256, 6), blk, 0, stream>>>(tp);

    // ---- L1: 1x1, 512->256, 38x38, P=23104, K=512, Z=1 (362 blocks)
    adder_conv<false, false><<<dim3(181, 2, 1), blk, 0, stream>>>(
        x, wT[0], nullptr, part, 512, 38, 38, 38, 256, 1, 0, 16, 23104, 1444, 23104);
    combine_stats<<<dim3(256, 16), blk, 0, stream>>>(part, bufA, st + stOff[0], 256, 1444, 1, 23104);
    ab_kernel<<<1, blk, 0, stream>>>(st + stOff[0], g[0], bt[0], ab + abOff[0], 256, 1.0 / 23104);

    // ---- L2: 3x3 s2 p1, 256->512, 38->19, P=5776, K=2304, Z=2 (368 blocks)
    adder_conv<true, true><<<dim3(46, 4, 2), blk, 0, stream>>>(
        bufA, wT[1], ab + abOff[0], part, 256, 38, 38, 19, 512, 2, 1, 36, 5776, 361, 5776);
    combine_stats<<<dim3(512, 16), blk, 0, stream>>>(part, bufB, st + stOff[1], 512, 361, 2, 5776);
    ab_kernel<<<2, blk, 0, stream>>>(st + stOff[1], g[1], bt[1], ab + abOff[1], 512, 1.0 / 5776);

    // ---- L3: 1x1, 512->128, 19x19, P=5776, K=512, Z=8 (368 blocks)
    adder_conv<false, true><<<dim3(46, 1, 8), blk, 0, stream>>>(
        bufB, wT[2], ab + abOff[1], part, 512, 19, 19, 19, 128, 1, 0, 2, 5776, 361, 5776);
    combine_stats<<<dim3(128, 16), blk, 0, stream>>>(part, bufA, st + stOff[2], 128, 361, 8, 5776);
    ab_kernel<<<1, blk, 0, stream>>>(st + stOff[2], g[2], bt[2], ab + abOff[2], 128, 1.0 / 5776);

    // ---- L4: 3x3 s2 p1, 128->256, 19->10, P=1600, K=1152, Z=12 (312 blocks)
    adder_conv<true, true><<<dim3(13, 2, 12), blk, 0, stream>>>(
        bufA, wT[3], ab + abOff[2], part, 128, 19, 19, 10, 256, 2, 1, 3, 1600, 100, 1600);
    combine_stats<<<dim3(256, 16), blk, 0, stream>>>(part, bufB, st + stOff[3], 256, 100, 12, 1600);
    ab_kernel<<<1, blk, 0, stream>>>(st + stOff[3], g[3], bt[3], ab + abOff[3], 256, 1.0 / 1600);

    // ---- L5: 1x1, 256->128, 10x10, P=1600, K=256, Z=8 (104 blocks)
    adder_conv<false, true><<<dim3(13, 1, 8), blk, 0, stream>>>(
        bufB, wT[4], ab + abOff[3], part, 256, 10, 10, 10, 128, 1, 0, 1, 1600, 100, 1600);
    combine_stats<<<dim3(128, 16), blk, 0, stream>>>(part, bufA, st + stOff[4], 128, 100, 8, 1600);
    ab_kernel<<<1, blk, 0, stream>>>(st + stOff[4], g[4], bt[4], ab + abOff[4], 128, 1.0 / 1600);

    // ---- L6: 3x3 s2 p0, 128->256, 10->4, P=256, K=1152, Z=18 (72 blocks)
    adder_conv<true, true><<<dim3(2, 2, 18), blk, 0, stream>>>(
        bufA, wT[5], ab + abOff[4], part, 128, 10, 10, 4, 256, 2, 0, 2, 256, 16, 256);
    combine_stats<<<dim3(256, 16), blk, 0, stream>>>(part, bufB, st + stOff[5], 256, 16, 18, 256);
    ab_kernel<<<1, blk, 0, stream>>>(st + stOff[5], g[5], bt[5], ab + abOff[5], 256, 1.0 / 256);

    // ---- final BN+ReLU6 -> out
    apply_kernel<<<(65536 + 255) / 256, blk, 0, stream>>>(bufB, ab + abOff[5], (float*)d_out,
                                                          65536, 256, 16);
}

// Round 10
// 656.352 us; speedup vs baseline: 1.2261x; 1.2261x over previous
//
#include <hip/hip_runtime.h>

// ---------------------------------------------------------------------------
// AdderNet 6-layer stack on MI355X (gfx950).
// out[n,o,p] = -sum_k |patch[p,k] - w[o,k]|
//
// Geometry frontier for L2 (P=5776,K=2304):
//   R8  64x64 4x4: 2.0 B/upd, 42% occ -> 314us
//   R10 64x128 4x8: 1.5 B/upd, 24% occ -> 308us
//   R12 128x128 8x8: 1.0 B/upd, 13% occ -> 383us  (REGRESSION: grid-starved)
// => inner loop is latency-bound per wave; occupancy is the currency; DS-per-
//    update gains that cost grid size are net-negative.
// R13: revert kernel to R10 (byte-identical, VGPR 44), change ONLY grid/Z:
//    runtime-gated big part buffer (47.3MB if ws_size allows) unlocks
//    L1 Z=2, L2 Z=4, L3 Z=16, L4 Z=18, L6 Z=36 -> 2x blocks on the two
//    dominant layers (L2: 728->1456 = 5.7/CU). Fallback = R10 config exactly.
// ---------------------------------------------------------------------------

#define QSCALE 131072.0f            /* 2^17 */
#define QBIAS  1048576.5f           /* 2^20 + 0.5 (round via trunc) */
#define QINV   7.62939453125e-06    /* 2^-17 */

template <bool IS3x3, bool BN>
__global__ __launch_bounds__(256, 4)
void adder_conv(const float* __restrict__ x, const unsigned* __restrict__ wT,
                const float2* __restrict__ ab, unsigned* __restrict__ part,
                int Cin, int H, int W, int Wo, int Cout,
                int stride, int pad, int cpz, int P, int PI, int Pp)
{
    constexpr int KC = 32;
    __shared__ unsigned xs[KC][68];  // 64 pix, stride 68: conflict-light
    __shared__ unsigned ws[KC][128]; // 128 och
    __shared__ float2 abls[512];

    const int t  = threadIdx.x;
    const int tx = t & 15, ty = t >> 4;          // compute: 4 pix x 8 och
    const int ptile = blockIdx.x * 64, otile = blockIdx.y * 128;
    const int pp = t & 63, rg = t >> 6;          // xs staging: pixel, k-group
    const int oq = t & 31, kr = t >> 5;          // ws staging: och-quad, k-row

    if (BN) {
        for (int i = t; i < Cin; i += 256) abls[i] = ab[i];
        __syncthreads();
    }

    // staging pixel decode (fixed per thread)
    const int p_st = ptile + pp;
    const bool pv = p_st < P;
    int n_st = 0, q = 0;
    if (pv) { n_st = p_st / PI; q = p_st - n_st * PI; }
    const int oh = q / Wo, ow = q - oh * Wo;
    const int ih0 = oh * stride - pad, iw0 = ow * stride - pad;
    const int HWi = H * W;
    const float* xb = x + (size_t)n_st * Cin * HWi;
    const unsigned* wbase = wT + otile + oq * 4;

    unsigned acc[4][8] = {};

    const int chunkBeg = blockIdx.z * cpz, chunkEnd = chunkBeg + cpz;

    // ---- prefetch state: NAMED scalars only
    float xr0, xr1, xr2, xr3, xr4, xr5, xr6, xr7;
    uint4 wr0, wr1, wr2, wr3;
    int c0P = 0; bool vP = false;

#define ISSUE(CH) do {                                                        \
        const int k0_ = (CH) * KC;                                            \
        int c0_, ih_, iw_;                                                    \
        if (IS3x3) {                                                          \
            const int tap_ = k0_ / Cin;          /* uniform: Cin%32==0 */     \
            c0_ = k0_ - tap_ * Cin;                                           \
            const int kh_ = tap_ / 3, kw_ = tap_ - kh_ * 3;                   \
            ih_ = ih0 + kh_; iw_ = iw0 + kw_;                                 \
        } else { c0_ = k0_; ih_ = ih0; iw_ = iw0; }                           \
        vP = pv && (!IS3x3 || (ih_ >= 0 && ih_ < H && iw_ >= 0 && iw_ < W));  \
        c0P = c0_;                                                            \
        const float* px_ = xb + (size_t)(c0_ + rg) * HWi + (ih_ * W + iw_);   \
        xr0 = vP ? px_[0] : 0.f;                                              \
        xr1 = vP ? px_[(size_t) 4 * HWi] : 0.f;                               \
        xr2 = vP ? px_[(size_t) 8 * HWi] : 0.f;                               \
        xr3 = vP ? px_[(size_t)12 * HWi] : 0.f;                               \
        xr4 = vP ? px_[(size_t)16 * HWi] : 0.f;                               \
        xr5 = vP ? px_[(size_t)20 * HWi] : 0.f;                               \
        xr6 = vP ? px_[(size_t)24 * HWi] : 0.f;                               \
        xr7 = vP ? px_[(size_t)28 * HWi] : 0.f;                               \
        const unsigned* pw_ = wbase + (size_t)(k0_ + kr) * Cout;              \
        wr0 = *(const uint4*)(pw_);                                           \
        wr1 = *(const uint4*)(pw_ + (size_t) 8 * Cout);                       \
        wr2 = *(const uint4*)(pw_ + (size_t)16 * Cout);                       \
        wr3 = *(const uint4*)(pw_ + (size_t)24 * Cout);                       \
    } while (0)

    // BN (optional) then quantize: u = trunc(v*2^17 + 2^20 + 0.5)
#define BNQ(V, J, DST)                                                        \
        {                                                                     \
            float vv_ = V;                                                    \
            if (BN) {                                                         \
                const float2 s_ = abls[c0P + rg + 4 * (J)];                   \
                vv_ = fminf(fmaxf(fmaf(s_.x, vv_, s_.y), 0.f), 6.f);          \
                vv_ = vP ? vv_ : 0.f;      /* padding stays literal 0 */      \
            }                                                                 \
            DST = (unsigned)fmaf(vv_, QSCALE, QBIAS);                         \
        }

#define WRITE_LDS() do {                                                      \
        unsigned q0_, q1_, q2_, q3_, q4_, q5_, q6_, q7_;                      \
        BNQ(xr0, 0, q0_) BNQ(xr1, 1, q1_) BNQ(xr2, 2, q2_) BNQ(xr3, 3, q3_)   \
        BNQ(xr4, 4, q4_) BNQ(xr5, 5, q5_) BNQ(xr6, 6, q6_) BNQ(xr7, 7, q7_)   \
        xs[rg     ][pp] = q0_; xs[rg +  4][pp] = q1_;                         \
        xs[rg +  8][pp] = q2_; xs[rg + 12][pp] = q3_;                         \
        xs[rg + 16][pp] = q4_; xs[rg + 20][pp] = q5_;                         \
        xs[rg + 24][pp] = q6_; xs[rg + 28][pp] = q7_;                         \
        *(uint4*)&ws[kr     ][oq * 4] = wr0;                                  \
        *(uint4*)&ws[kr +  8][oq * 4] = wr1;                                  \
        *(uint4*)&ws[kr + 16][oq * 4] = wr2;                                  \
        *(uint4*)&ws[kr + 24][oq * 4] = wr3;                                  \
    } while (0)

    ISSUE(chunkBeg);

    for (int ch = chunkBeg; ch < chunkEnd; ++ch) {
        // [A] regs -> LDS (BN + quantize fused)
        WRITE_LDS();
        // [B] issue next chunk's global loads (vmcnt never drained in-loop)
        if (ch + 1 < chunkEnd) ISSUE(ch + 1);
        // [C] only the LDS writes must be visible before the barrier
        asm volatile("s_waitcnt lgkmcnt(0)" ::: "memory");
        __builtin_amdgcn_s_barrier();
        asm volatile("" ::: "memory");

        // ---- inner: 3 ds_read_b128 + 32 v_sad_u32 per kk
#pragma unroll 2
        for (int kk = 0; kk < KC; ++kk) {
            const uint4 xv = *(const uint4*)&xs[kk][tx * 4];
            const uint4 wa = *(const uint4*)&ws[kk][ty * 8];
            const uint4 wb = *(const uint4*)&ws[kk][ty * 8 + 4];
#define S1(A, XC, WC) asm("v_sad_u32 %0, %1, %2, %0" : "+v"(A) : "v"(XC), "v"(WC));
#define SROW(I, XC)                                             \
            S1(acc[I][0], XC, wa.x) S1(acc[I][1], XC, wa.y)     \
            S1(acc[I][2], XC, wa.z) S1(acc[I][3], XC, wa.w)     \
            S1(acc[I][4], XC, wb.x) S1(acc[I][5], XC, wb.y)     \
            S1(acc[I][6], XC, wb.z) S1(acc[I][7], XC, wb.w)
            SROW(0, xv.x) SROW(1, xv.y) SROW(2, xv.z) SROW(3, xv.w)
#undef SROW
#undef S1
        }
        asm volatile("" ::: "memory");
        __builtin_amdgcn_s_barrier();
        asm volatile("" ::: "memory");
    }
#undef ISSUE
#undef BNQ
#undef WRITE_LDS

    // ---- plain coalesced stores into this z-slice's partial buffer
    const int p0 = ptile + tx * 4;
    const bool full = (p0 + 3) < P;
#pragma unroll
    for (int jj = 0; jj < 8; ++jj) {
        const int o = otile + ty * 8 + jj;
        unsigned* dst = part + ((size_t)blockIdx.z * Cout + o) * Pp + p0;
        if (full) {
            *(uint4*)dst = make_uint4(acc[0][jj], acc[1][jj], acc[2][jj], acc[3][jj]);
        } else {
#pragma unroll
            for (int i = 0; i < 4; ++i)
                if (p0 + i < P) dst[i] = acc[i][jj];
        }
    }
}

// fused: sum Z u32 partial slices, rescale + negate -> float [n][c][PI], and
// accumulate per-channel sum/sumsq (double) for BN stats.
__global__ void combine_stats(const unsigned* __restrict__ part, float* __restrict__ fin,
                              double* __restrict__ st, int C, int PI, int Z, int Pp)
{
    const int c = blockIdx.x, n = blockIdx.y, t = threadIdx.x;
    const int pbase = n * PI;
    double s = 0.0, s2 = 0.0;
    for (int qq = t; qq < PI; qq += 256) {
        unsigned long long u = 0;
        for (int z = 0; z < Z; ++z)
            u += part[((size_t)z * C + c) * Pp + pbase + qq];
        const float v = -(float)((double)u * QINV);
        fin[((size_t)n * C + c) * PI + qq] = v;
        s += v; s2 += (double)v * v;
    }
    __shared__ double sh[256], sh2[256];
    sh[t] = s; sh2[t] = s2; __syncthreads();
    for (int off = 128; off > 0; off >>= 1) {
        if (t < off) { sh[t] += sh[t + off]; sh2[t] += sh2[t + off]; }
        __syncthreads();
    }
    if (t == 0) {
        unsafeAtomicAdd(&st[2 * c], sh[0]);
        unsafeAtomicAdd(&st[2 * c + 1], sh2[0]);
    }
}

// per-channel affine fold: a = g*rsqrt(var+eps), b = beta - mean*a
__global__ void ab_kernel(const double* __restrict__ st, const float* __restrict__ gamma,
                          const float* __restrict__ beta, float2* __restrict__ ab,
                          int C, double invCount)
{
    const int c = blockIdx.x * blockDim.x + threadIdx.x;
    if (c < C) {
        const double mean = st[2 * c] * invCount;
        const double var  = st[2 * c + 1] * invCount - mean * mean;
        const float a = gamma[c] * rsqrtf((float)var + 1e-5f);
        const float b = beta[c] - (float)mean * a;
        ab[c] = make_float2(a, b);
    }
}

// final BN+ReLU6 -> d_out
__global__ void apply_kernel(const float* __restrict__ y, const float2* __restrict__ ab,
                             float* __restrict__ out, int total, int C, int PI)
{
    const int i = blockIdx.x * 256 + threadIdx.x;
    if (i < total) {
        const int c = (i / PI) % C;
        const float2 s = ab[c];
        out[i] = fminf(fmaxf(fmaf(s.x, y[i], s.y), 0.f), 6.f);
    }
}

// merged weight transposes + fixed-point quantize:
// w [Cout][Cin][tap] -> wT [tap*Cin + c][Cout], u32 = round(w*2^17) + 2^20
struct TDesc { const float* w; unsigned* wT; int Cout; int Cin; int Tap; int elems; };
struct TPack { TDesc d[6]; };

__global__ void transpose_all(TPack p)
{
    const TDesc d = p.d[blockIdx.y];
    const int i = blockIdx.x * 256 + threadIdx.x;
    if (i < d.elems) {
        const int k = i / d.Cout, o = i - k * d.Cout;
        const int tap = k / d.Cin, c = k - tap * d.Cin;
        const float v = d.w[((size_t)o * d.Cin + c) * d.Tap + tap];
        d.wT[i] = (unsigned)fmaf(v, QSCALE, QBIAS);
    }
}

extern "C" void kernel_launch(void* const* d_in, const int* in_sizes, int n_in,
                              void* d_out, int out_size, void* d_ws, size_t ws_size,
                              hipStream_t stream)
{
    const float* x = (const float*)d_in[0];
    const float *w[6], *g[6], *bt[6];
    for (int i = 0; i < 6; ++i) {
        w[i]  = (const float*)d_in[1 + 3 * i];
        g[i]  = (const float*)d_in[2 + 3 * i];
        bt[i] = (const float*)d_in[3 + 3 * i];
    }

    // ---- runtime-gated part-buffer sizing: bigger part => more Z-splits
    const size_t partSmall = 23658496, partBig = 47316992;
    const size_t wTbytes = 7995392;                 // sum(wElems)*4
    const size_t fixedBytes = 23658496 + 11829248 + wTbytes + 3072 * 8 + 1536 * 8;
    const bool big = ws_size >= fixedBytes + partBig;
    const size_t partBytes = big ? partBig : partSmall;

    char* ws = (char*)d_ws;
    float* bufA = (float*)ws;                                   // 23,658,496 B
    float* bufB = (float*)(ws + 23658496);                      // 11,829,248 B
    unsigned* part = (unsigned*)(ws + 23658496 + 11829248);     // partBytes
    size_t off = 23658496 + 11829248 + partBytes;
    const int wElems[6] = {256 * 512, 512 * 2304, 128 * 512,
                           256 * 1152, 128 * 256, 256 * 1152};
    unsigned* wT[6];
    for (int i = 0; i < 6; ++i) { wT[i] = (unsigned*)(ws + off); off += (size_t)wElems[i] * 4; }
    double* st = (double*)(ws + off); off += 3072 * 8;
    float2* ab = (float2*)(ws + off);
    const int stOff[6] = {0, 512, 1536, 1792, 2304, 2560};
    const int abOff[6] = {0, 256, 768, 896, 1152, 1280};

    // Z-splits: big path doubles grid on dominant layers; fallback == R10.
    const int zL1 = big ? 2 : 1,  cpzL1 = 16 / zL1;
    const int zL2 = big ? 4 : 2,  cpzL2 = 72 / zL2;
    const int zL3 = big ? 16 : 8, cpzL3 = 16 / zL3;
    const int zL4 = big ? 18 : 12, cpzL4 = 36 / zL4;
    const int zL5 = 8,            cpzL5 = 1;
    const int zL6 = big ? 36 : 18, cpzL6 = 36 / zL6;

    const dim3 blk(256);

    // zero stats accumulators (ws is poisoned 0xAA before every launch)
    hipMemsetAsync(st, 0, 3072 * 8, stream);

    // merged weight transposes (tap-major k order) + quantize
    TPack tp;
    const int wCout[6] = {256, 512, 128, 256, 128, 256};
    const int wCin[6]  = {512, 256, 512, 128, 256, 128};
    const int wTap[6]  = {1, 9, 1, 9, 1, 9};
    for (int i = 0; i < 6; ++i)
        tp.d[i] = TDesc{w[i], wT[i], wCout[i], wCin[i], wTap[i], wElems[i]};
    transpose_all<<<dim3((1179648 + 255) / 256, 6), blk, 0, stream>>>(tp);

    // ---- L1: 1x1, 512->256, 38x38, P=23104, K=512
    adder_conv<false, false><<<dim3(361, 2, zL1), blk, 0, stream>>>(
        x, wT[0], nullptr, part, 512, 38, 38, 38, 256, 1, 0, cpzL1, 23104, 1444, 23104);
    combine_stats<<<dim3(256, 16), blk, 0, stream>>>(part, bufA, st + stOff[0], 256, 1444, zL1, 23104);
    ab_kernel<<<1, blk, 0, stream>>>(st + stOff[0], g[0], bt[0], ab + abOff[0], 256, 1.0 / 23104);

    // ---- L2: 3x3 s2 p1, 256->512, 38->19, P=5776, K=2304
    adder_conv<true, true><<<dim3(91, 4, zL2), blk, 0, stream>>>(
        bufA, wT[1], ab + abOff[0], part, 256, 38, 38, 19, 512, 2, 1, cpzL2, 5776, 361, 5776);
    combine_stats<<<dim3(512, 16), blk, 0, stream>>>(part, bufB, st + stOff[1], 512, 361, zL2, 5776);
    ab_kernel<<<2, blk, 0, stream>>>(st + stOff[1], g[1], bt[1], ab + abOff[1], 512, 1.0 / 5776);

    // ---- L3: 1x1, 512->128, 19x19, P=5776, K=512
    adder_conv<false, true><<<dim3(91, 1, zL3), blk, 0, stream>>>(
        bufB, wT[2], ab + abOff[1], part, 512, 19, 19, 19, 128, 1, 0, cpzL3, 5776, 361, 5776);
    combine_stats<<<dim3(128, 16), blk, 0, stream>>>(part, bufA, st + stOff[2], 128, 361, zL3, 5776);
    ab_kernel<<<1, blk, 0, stream>>>(st + stOff[2], g[2], bt[2], ab + abOff[2], 128, 1.0 / 5776);

    // ---- L4: 3x3 s2 p1, 128->256, 19->10, P=1600, K=1152
    adder_conv<true, true><<<dim3(25, 2, zL4), blk, 0, stream>>>(
        bufA, wT[3], ab + abOff[2], part, 128, 19, 19, 10, 256, 2, 1, cpzL4, 1600, 100, 1600);
    combine_stats<<<dim3(256, 16), blk, 0, stream>>>(part, bufB, st + stOff[3], 256, 100, zL4, 1600);
    ab_kernel<<<1, blk, 0, stream>>>(st + stOff[3], g[3], bt[3], ab + abOff[3], 256, 1.0 / 1600);

    // ---- L5: 1x1, 256->128, 10x10, P=1600, K=256
    adder_conv<false, true><<<dim3(25, 1, zL5), blk, 0, stream>>>(
        bufB, wT[4], ab + abOff[3], part, 256, 10, 10, 10, 128, 1, 0, cpzL5, 1600, 100, 1600);
    combine_stats<<<dim3(128, 16), blk, 0, stream>>>(part, bufA, st + stOff[4], 128, 100, zL5, 1600);
    ab_kernel<<<1, blk, 0, stream>>>(st + stOff[4], g[4], bt[4], ab + abOff[4], 128, 1.0 / 1600);

    // ---- L6: 3x3 s2 p0, 128->256, 10->4, P=256, K=1152
    adder_conv<true, true><<<dim3(4, 2, zL6), blk, 0, stream>>>(
        bufA, wT[5], ab + abOff[4], part, 128, 10, 10, 4, 256, 2, 0, cpzL6, 256, 16, 256);
    combine_stats<<<dim3(256, 16), blk, 0, stream>>>(part, bufB, st + stOff[5], 256, 16, zL6, 256);
    ab_kernel<<<1, blk, 0, stream>>>(st + stOff[5], g[5], bt[5], ab + abOff[5], 256, 1.0 / 256);

    // ---- final BN+ReLU6 -> out
    apply_kernel<<<(65536 + 255) / 256, blk, 0, stream>>>(bufB, ab + abOff[5], (float*)d_out,
                                                          65536, 256, 16);
}

// Round 11
// 647.123 us; speedup vs baseline: 1.2436x; 1.0143x over previous
//
#include <hip/hip_runtime.h>

// ---------------------------------------------------------------------------
// AdderNet 6-layer stack on MI355X (gfx950).
// out[n,o,p] = -sum_k |patch[p,k] - w[o,k]|
//
// L2 geometry frontier (P=5776,K=2304):
//   64x64 4x4 (2.0 B/upd, 42% occ) 314 | 64x128 4x8 (1.5, 24%) 308 |
//   128x128 8x8 (1.0, 13%) 383 REGRESS | 64x128 4x8 +Z=4 (1.5, 39%) 283.
// Model: LDS floor @1.5B/upd = 196us, running at 69% eff; occupancy beyond
// ~25% has weak returns; bytes/update is the lever IF grid stays >= ~2.8/CU.
// R14: OCH=256 template path for L1+L2: 64x256 tile, 8 pix x 8 och micro
//   (thread grid 8x32) = 4 ds_read_b128 / 64 updates = 1.0 B/upd with
//   728/722-block grids (~2.8/CU at the 3-block LDS cap). All LDS patterns
//   8-way-broadcast or contiguous (conflict-free). L3-L6 unchanged (OCH=128).
// ---------------------------------------------------------------------------

#define QSCALE 131072.0f            /* 2^17 */
#define QBIAS  1048576.5f           /* 2^20 + 0.5 (round via trunc) */
#define QINV   7.62939453125e-06    /* 2^-17 */

template <bool IS3x3, bool BN, int OCH>
__global__ __launch_bounds__(256, OCH == 256 ? 3 : 4)
void adder_conv(const float* __restrict__ x, const unsigned* __restrict__ wT,
                const float2* __restrict__ ab, unsigned* __restrict__ part,
                int Cin, int H, int W, int Wo, int Cout,
                int stride, int pad, int cpz, int P, int PI, int Pp)
{
    constexpr int KC = 32;
    __shared__ unsigned xs[KC][68];   // 64 pix, stride 68: conflict-light
    __shared__ unsigned ws[KC][OCH];  // 128 or 256 och
    __shared__ float2 abls[512];

    const int t  = threadIdx.x;
    // compute-thread mapping: OCH=128 -> 16x16 (4 pix x 8 och);
    //                         OCH=256 -> 8x32  (8 pix x 8 och, two halves)
    const int px = (OCH == 256) ? (t & 7) : (t & 15);
    const int oc = (OCH == 256) ? (t >> 3) : (t >> 4);
    const int ptile = blockIdx.x * 64, otile = blockIdx.y * OCH;
    const int pp = t & 63, rg = t >> 6;          // xs staging: pixel, k-group
    // ws staging: OCH=128: 32 och-quads x 8 k-rows; OCH=256: 64 quads x 4 rows
    const int woq = (OCH == 256) ? (t & 63) : (t & 31);
    const int wkr = (OCH == 256) ? (t >> 6) : (t >> 5);
    constexpr int WSTEP = (OCH == 256) ? 4 : 8;

    if (BN) {
        for (int i = t; i < Cin; i += 256) abls[i] = ab[i];
        __syncthreads();
    }

    // staging pixel decode (fixed per thread)
    const int p_st = ptile + pp;
    const bool pv = p_st < P;
    int n_st = 0, q = 0;
    if (pv) { n_st = p_st / PI; q = p_st - n_st * PI; }
    const int oh = q / Wo, ow = q - oh * Wo;
    const int ih0 = oh * stride - pad, iw0 = ow * stride - pad;
    const int HWi = H * W;
    const float* xb = x + (size_t)n_st * Cin * HWi;
    const unsigned* wbase = wT + otile + woq * 4;

    unsigned acc[4][8] = {};      // OCH=128 path
    unsigned acc2[2][4][8] = {};  // OCH=256 path [pix-half][pix][och 0-3 lo,4-7 hi]

    const int chunkBeg = blockIdx.z * cpz, chunkEnd = chunkBeg + cpz;

    // ---- prefetch state: NAMED scalars only
    float xr0, xr1, xr2, xr3, xr4, xr5, xr6, xr7;
    uint4 wr0, wr1, wr2, wr3, wr4, wr5, wr6, wr7;
    int c0P = 0; bool vP = false;

#define ISSUE(CH) do {                                                        \
        const int k0_ = (CH) * KC;                                            \
        int c0_, ih_, iw_;                                                    \
        if (IS3x3) {                                                          \
            const int tap_ = k0_ / Cin;          /* uniform: Cin%32==0 */     \
            c0_ = k0_ - tap_ * Cin;                                           \
            const int kh_ = tap_ / 3, kw_ = tap_ - kh_ * 3;                   \
            ih_ = ih0 + kh_; iw_ = iw0 + kw_;                                 \
        } else { c0_ = k0_; ih_ = ih0; iw_ = iw0; }                           \
        vP = pv && (!IS3x3 || (ih_ >= 0 && ih_ < H && iw_ >= 0 && iw_ < W));  \
        c0P = c0_;                                                            \
        const float* px_ = xb + (size_t)(c0_ + rg) * HWi + (ih_ * W + iw_);   \
        xr0 = vP ? px_[0] : 0.f;                                              \
        xr1 = vP ? px_[(size_t) 4 * HWi] : 0.f;                               \
        xr2 = vP ? px_[(size_t) 8 * HWi] : 0.f;                               \
        xr3 = vP ? px_[(size_t)12 * HWi] : 0.f;                               \
        xr4 = vP ? px_[(size_t)16 * HWi] : 0.f;                               \
        xr5 = vP ? px_[(size_t)20 * HWi] : 0.f;                               \
        xr6 = vP ? px_[(size_t)24 * HWi] : 0.f;                               \
        xr7 = vP ? px_[(size_t)28 * HWi] : 0.f;                               \
        const unsigned* pw_ = wbase + (size_t)(k0_ + wkr) * Cout;             \
        wr0 = *(const uint4*)(pw_);                                           \
        wr1 = *(const uint4*)(pw_ + (size_t)(1 * WSTEP) * Cout);              \
        wr2 = *(const uint4*)(pw_ + (size_t)(2 * WSTEP) * Cout);              \
        wr3 = *(const uint4*)(pw_ + (size_t)(3 * WSTEP) * Cout);              \
        if (OCH == 256) {                                                     \
            wr4 = *(const uint4*)(pw_ + (size_t)(4 * WSTEP) * Cout);          \
            wr5 = *(const uint4*)(pw_ + (size_t)(5 * WSTEP) * Cout);          \
            wr6 = *(const uint4*)(pw_ + (size_t)(6 * WSTEP) * Cout);          \
            wr7 = *(const uint4*)(pw_ + (size_t)(7 * WSTEP) * Cout);          \
        }                                                                     \
    } while (0)

    // BN (optional) then quantize: u = trunc(v*2^17 + 2^20 + 0.5)
#define BNQ(V, J, DST)                                                        \
        {                                                                     \
            float vv_ = V;                                                    \
            if (BN) {                                                         \
                const float2 s_ = abls[c0P + rg + 4 * (J)];                   \
                vv_ = fminf(fmaxf(fmaf(s_.x, vv_, s_.y), 0.f), 6.f);          \
                vv_ = vP ? vv_ : 0.f;      /* padding stays literal 0 */      \
            }                                                                 \
            DST = (unsigned)fmaf(vv_, QSCALE, QBIAS);                         \
        }

#define WRITE_LDS() do {                                                      \
        unsigned q0_, q1_, q2_, q3_, q4_, q5_, q6_, q7_;                      \
        BNQ(xr0, 0, q0_) BNQ(xr1, 1, q1_) BNQ(xr2, 2, q2_) BNQ(xr3, 3, q3_)   \
        BNQ(xr4, 4, q4_) BNQ(xr5, 5, q5_) BNQ(xr6, 6, q6_) BNQ(xr7, 7, q7_)   \
        xs[rg     ][pp] = q0_; xs[rg +  4][pp] = q1_;                         \
        xs[rg +  8][pp] = q2_; xs[rg + 12][pp] = q3_;                         \
        xs[rg + 16][pp] = q4_; xs[rg + 20][pp] = q5_;                         \
        xs[rg + 24][pp] = q6_; xs[rg + 28][pp] = q7_;                         \
        *(uint4*)&ws[wkr            ][woq * 4] = wr0;                         \
        *(uint4*)&ws[wkr + 1 * WSTEP][woq * 4] = wr1;                         \
        *(uint4*)&ws[wkr + 2 * WSTEP][woq * 4] = wr2;                         \
        *(uint4*)&ws[wkr + 3 * WSTEP][woq * 4] = wr3;                         \
        if (OCH == 256) {                                                     \
            *(uint4*)&ws[wkr + 4 * WSTEP][woq * 4] = wr4;                     \
            *(uint4*)&ws[wkr + 5 * WSTEP][woq * 4] = wr5;                     \
            *(uint4*)&ws[wkr + 6 * WSTEP][woq * 4] = wr6;                     \
            *(uint4*)&ws[wkr + 7 * WSTEP][woq * 4] = wr7;                     \
        }                                                                     \
    } while (0)

    ISSUE(chunkBeg);

    for (int ch = chunkBeg; ch < chunkEnd; ++ch) {
        // [A] regs -> LDS (BN + quantize fused)
        WRITE_LDS();
        // [B] issue next chunk's global loads (vmcnt never drained in-loop)
        if (ch + 1 < chunkEnd) ISSUE(ch + 1);
        // [C] only the LDS writes must be visible before the barrier
        asm volatile("s_waitcnt lgkmcnt(0)" ::: "memory");
        __builtin_amdgcn_s_barrier();
        asm volatile("" ::: "memory");

#define S1(A, XC, WC) asm("v_sad_u32 %0, %1, %2, %0" : "+v"(A) : "v"(XC), "v"(WC));
        if (OCH == 128) {
            // ---- inner: 3 ds_read_b128 + 32 v_sad_u32 per kk
#pragma unroll 2
            for (int kk = 0; kk < KC; ++kk) {
                const uint4 xv = *(const uint4*)&xs[kk][px * 4];
                const uint4 wa = *(const uint4*)&ws[kk][oc * 8];
                const uint4 wb = *(const uint4*)&ws[kk][oc * 8 + 4];
#define SROW(I, XC)                                             \
                S1(acc[I][0], XC, wa.x) S1(acc[I][1], XC, wa.y) \
                S1(acc[I][2], XC, wa.z) S1(acc[I][3], XC, wa.w) \
                S1(acc[I][4], XC, wb.x) S1(acc[I][5], XC, wb.y) \
                S1(acc[I][6], XC, wb.z) S1(acc[I][7], XC, wb.w)
                SROW(0, xv.x) SROW(1, xv.y) SROW(2, xv.z) SROW(3, xv.w)
#undef SROW
            }
        } else {
            // ---- inner: 4 ds_read_b128 + 64 v_sad_u32 per kk
#pragma unroll 2
            for (int kk = 0; kk < KC; ++kk) {
                const uint4 xlo = *(const uint4*)&xs[kk][px * 4];
                const uint4 xhi = *(const uint4*)&xs[kk][32 + px * 4];
                const uint4 wlo = *(const uint4*)&ws[kk][oc * 4];
                const uint4 whi = *(const uint4*)&ws[kk][128 + oc * 4];
#define SROW(a, i, XC)                                                \
                S1(acc2[a][i][0], XC, wlo.x) S1(acc2[a][i][1], XC, wlo.y) \
                S1(acc2[a][i][2], XC, wlo.z) S1(acc2[a][i][3], XC, wlo.w) \
                S1(acc2[a][i][4], XC, whi.x) S1(acc2[a][i][5], XC, whi.y) \
                S1(acc2[a][i][6], XC, whi.z) S1(acc2[a][i][7], XC, whi.w)
                SROW(0, 0, xlo.x) SROW(0, 1, xlo.y) SROW(0, 2, xlo.z) SROW(0, 3, xlo.w)
                SROW(1, 0, xhi.x) SROW(1, 1, xhi.y) SROW(1, 2, xhi.z) SROW(1, 3, xhi.w)
#undef SROW
            }
        }
#undef S1
        asm volatile("" ::: "memory");
        __builtin_amdgcn_s_barrier();
        asm volatile("" ::: "memory");
    }
#undef ISSUE
#undef BNQ
#undef WRITE_LDS

    // ---- plain coalesced stores into this z-slice's partial buffer
    if (OCH == 128) {
        const int p0 = ptile + px * 4;
        const bool full = (p0 + 3) < P;
#pragma unroll
        for (int jj = 0; jj < 8; ++jj) {
            const int o = otile + oc * 8 + jj;
            unsigned* dst = part + ((size_t)blockIdx.z * Cout + o) * Pp + p0;
            if (full) {
                *(uint4*)dst = make_uint4(acc[0][jj], acc[1][jj], acc[2][jj], acc[3][jj]);
            } else {
#pragma unroll
                for (int i = 0; i < 4; ++i)
                    if (p0 + i < P) dst[i] = acc[i][jj];
            }
        }
    } else {
#pragma unroll
        for (int a = 0; a < 2; ++a) {
            const int p0 = ptile + a * 32 + px * 4;
            const bool full = (p0 + 3) < P;
#pragma unroll
            for (int jj = 0; jj < 8; ++jj) {
                const int o = otile + (jj < 4 ? oc * 4 + jj : 128 + oc * 4 + (jj - 4));
                unsigned* dst = part + ((size_t)blockIdx.z * Cout + o) * Pp + p0;
                if (full) {
                    *(uint4*)dst = make_uint4(acc2[a][0][jj], acc2[a][1][jj],
                                              acc2[a][2][jj], acc2[a][3][jj]);
                } else {
#pragma unroll
                    for (int i = 0; i < 4; ++i)
                        if (p0 + i < P) dst[i] = acc2[a][i][jj];
                }
            }
        }
    }
}

// fused: sum Z u32 partial slices, rescale + negate -> float [n][c][PI], and
// accumulate per-channel sum/sumsq (double) for BN stats.
__global__ void combine_stats(const unsigned* __restrict__ part, float* __restrict__ fin,
                              double* __restrict__ st, int C, int PI, int Z, int Pp)
{
    const int c = blockIdx.x, n = blockIdx.y, t = threadIdx.x;
    const int pbase = n * PI;
    double s = 0.0, s2 = 0.0;
    for (int qq = t; qq < PI; qq += 256) {
        unsigned long long u = 0;
        for (int z = 0; z < Z; ++z)
            u += part[((size_t)z * C + c) * Pp + pbase + qq];
        const float v = -(float)((double)u * QINV);
        fin[((size_t)n * C + c) * PI + qq] = v;
        s += v; s2 += (double)v * v;
    }
    __shared__ double sh[256], sh2[256];
    sh[t] = s; sh2[t] = s2; __syncthreads();
    for (int off = 128; off > 0; off >>= 1) {
        if (t < off) { sh[t] += sh[t + off]; sh2[t] += sh2[t + off]; }
        __syncthreads();
    }
    if (t == 0) {
        unsafeAtomicAdd(&st[2 * c], sh[0]);
        unsafeAtomicAdd(&st[2 * c + 1], sh2[0]);
    }
}

// per-channel affine fold: a = g*rsqrt(var+eps), b = beta - mean*a
__global__ void ab_kernel(const double* __restrict__ st, const float* __restrict__ gamma,
                          const float* __restrict__ beta, float2* __restrict__ ab,
                          int C, double invCount)
{
    const int c = blockIdx.x * blockDim.x + threadIdx.x;
    if (c < C) {
        const double mean = st[2 * c] * invCount;
        const double var  = st[2 * c + 1] * invCount - mean * mean;
        const float a = gamma[c] * rsqrtf((float)var + 1e-5f);
        const float b = beta[c] - (float)mean * a;
        ab[c] = make_float2(a, b);
    }
}

// final BN+ReLU6 -> d_out
__global__ void apply_kernel(const float* __restrict__ y, const float2* __restrict__ ab,
                             float* __restrict__ out, int total, int C, int PI)
{
    const int i = blockIdx.x * 256 + threadIdx.x;
    if (i < total) {
        const int c = (i / PI) % C;
        const float2 s = ab[c];
        out[i] = fminf(fmaxf(fmaf(s.x, y[i], s.y), 0.f), 6.f);
    }
}

// merged weight transposes + fixed-point quantize:
// w [Cout][Cin][tap] -> wT [tap*Cin + c][Cout], u32 = round(w*2^17) + 2^20
struct TDesc { const float* w; unsigned* wT; int Cout; int Cin; int Tap; int elems; };
struct TPack { TDesc d[6]; };

__global__ void transpose_all(TPack p)
{
    const TDesc d = p.d[blockIdx.y];
    const int i = blockIdx.x * 256 + threadIdx.x;
    if (i < d.elems) {
        const int k = i / d.Cout, o = i - k * d.Cout;
        const int tap = k / d.Cin, c = k - tap * d.Cin;
        const float v = d.w[((size_t)o * d.Cin + c) * d.Tap + tap];
        d.wT[i] = (unsigned)fmaf(v, QSCALE, QBIAS);
    }
}

extern "C" void kernel_launch(void* const* d_in, const int* in_sizes, int n_in,
                              void* d_out, int out_size, void* d_ws, size_t ws_size,
                              hipStream_t stream)
{
    const float* x = (const float*)d_in[0];
    const float *w[6], *g[6], *bt[6];
    for (int i = 0; i < 6; ++i) {
        w[i]  = (const float*)d_in[1 + 3 * i];
        g[i]  = (const float*)d_in[2 + 3 * i];
        bt[i] = (const float*)d_in[3 + 3 * i];
    }

    // ---- runtime-gated part-buffer sizing: bigger part => more Z-splits
    const size_t partSmall = 23658496, partBig = 47316992;
    const size_t wTbytes = 7995392;                 // sum(wElems)*4
    const size_t fixedBytes = 23658496 + 11829248 + wTbytes + 3072 * 8 + 1536 * 8;
    const bool big = ws_size >= fixedBytes + partBig;
    const size_t partBytes = big ? partBig : partSmall;

    char* ws = (char*)d_ws;
    float* bufA = (float*)ws;                                   // 23,658,496 B
    float* bufB = (float*)(ws + 23658496);                      // 11,829,248 B
    unsigned* part = (unsigned*)(ws + 23658496 + 11829248);     // partBytes
    size_t off = 23658496 + 11829248 + partBytes;
    const int wElems[6] = {256 * 512, 512 * 2304, 128 * 512,
                           256 * 1152, 128 * 256, 256 * 1152};
    unsigned* wT[6];
    for (int i = 0; i < 6; ++i) { wT[i] = (unsigned*)(ws + off); off += (size_t)wElems[i] * 4; }
    double* st = (double*)(ws + off); off += 3072 * 8;
    float2* ab = (float2*)(ws + off);
    const int stOff[6] = {0, 512, 1536, 1792, 2304, 2560};
    const int abOff[6] = {0, 256, 768, 896, 1152, 1280};

    // Z-splits (L1/L2 sized for the OCH=256 tile; fallback fits small part)
    const int zL1 = big ? 2 : 1,   cpzL1 = 16 / zL1;
    const int zL2 = big ? 4 : 2,   cpzL2 = 72 / zL2;
    const int zL3 = big ? 16 : 8,  cpzL3 = 16 / zL3;
    const int zL4 = big ? 18 : 12, cpzL4 = 36 / zL4;
    const int zL5 = 8,             cpzL5 = 1;
    const int zL6 = big ? 36 : 18, cpzL6 = 36 / zL6;

    const dim3 blk(256);

    // zero stats accumulators (ws is poisoned 0xAA before every launch)
    hipMemsetAsync(st, 0, 3072 * 8, stream);

    // merged weight transposes (tap-major k order) + quantize
    TPack tp;
    const int wCout[6] = {256, 512, 128, 256, 128, 256};
    const int wCin[6]  = {512, 256, 512, 128, 256, 128};
    const int wTap[6]  = {1, 9, 1, 9, 1, 9};
    for (int i = 0; i < 6; ++i)
        tp.d[i] = TDesc{w[i], wT[i], wCout[i], wCin[i], wTap[i], wElems[i]};
    transpose_all<<<dim3((1179648 + 255) / 256, 6), blk, 0, stream>>>(tp);

    // ---- L1: 1x1, 512->256, 38x38, P=23104, K=512 (OCH=256: 361x1xZ)
    adder_conv<false, false, 256><<<dim3(361, 1, zL1), blk, 0, stream>>>(
        x, wT[0], nullptr, part, 512, 38, 38, 38, 256, 1, 0, cpzL1, 23104, 1444, 23104);
    combine_stats<<<dim3(256, 16), blk, 0, stream>>>(part, bufA, st + stOff[0], 256, 1444, zL1, 23104);
    ab_kernel<<<1, blk, 0, stream>>>(st + stOff[0], g[0], bt[0], ab + abOff[0], 256, 1.0 / 23104);

    // ---- L2: 3x3 s2 p1, 256->512, 38->19, P=5776, K=2304 (OCH=256: 91x2xZ)
    adder_conv<true, true, 256><<<dim3(91, 2, zL2), blk, 0, stream>>>(
        bufA, wT[1], ab + abOff[0], part, 256, 38, 38, 19, 512, 2, 1, cpzL2, 5776, 361, 5776);
    combine_stats<<<dim3(512, 16), blk, 0, stream>>>(part, bufB, st + stOff[1], 512, 361, zL2, 5776);
    ab_kernel<<<2, blk, 0, stream>>>(st + stOff[1], g[1], bt[1], ab + abOff[1], 512, 1.0 / 5776);

    // ---- L3: 1x1, 512->128, 19x19, P=5776, K=512 (OCH=128)
    adder_conv<false, true, 128><<<dim3(91, 1, zL3), blk, 0, stream>>>(
        bufB, wT[2], ab + abOff[1], part, 512, 19, 19, 19, 128, 1, 0, cpzL3, 5776, 361, 5776);
    combine_stats<<<dim3(128, 16), blk, 0, stream>>>(part, bufA, st + stOff[2], 128, 361, zL3, 5776);
    ab_kernel<<<1, blk, 0, stream>>>(st + stOff[2], g[2], bt[2], ab + abOff[2], 128, 1.0 / 5776);

    // ---- L4: 3x3 s2 p1, 128->256, 19->10, P=1600, K=1152 (OCH=128)
    adder_conv<true, true, 128><<<dim3(25, 2, zL4), blk, 0, stream>>>(
        bufA, wT[3], ab + abOff[2], part, 128, 19, 19, 10, 256, 2, 1, cpzL4, 1600, 100, 1600);
    combine_stats<<<dim3(256, 16), blk, 0, stream>>>(part, bufB, st + stOff[3], 256, 100, zL4, 1600);
    ab_kernel<<<1, blk, 0, stream>>>(st + stOff[3], g[3], bt[3], ab + abOff[3], 256, 1.0 / 1600);

    // ---- L5: 1x1, 256->128, 10x10, P=1600, K=256 (OCH=128)
    adder_conv<false, true, 128><<<dim3(25, 1, zL5), blk, 0, stream>>>(
        bufB, wT[4], ab + abOff[3], part, 256, 10, 10, 10, 128, 1, 0, cpzL5, 1600, 100, 1600);
    combine_stats<<<dim3(128, 16), blk, 0, stream>>>(part, bufA, st + stOff[4], 128, 100, zL5, 1600);
    ab_kernel<<<1, blk, 0, stream>>>(st + stOff[4], g[4], bt[4], ab + abOff[4], 128, 1.0 / 1600);

    // ---- L6: 3x3 s2 p0, 128->256, 10->4, P=256, K=1152 (OCH=128)
    adder_conv<true, true, 128><<<dim3(4, 2, zL6), blk, 0, stream>>>(
        bufA, wT[5], ab + abOff[4], part, 128, 10, 10, 4, 256, 2, 0, cpzL6, 256, 16, 256);
    combine_stats<<<dim3(256, 16), blk, 0, stream>>>(part, bufB, st + stOff[5], 256, 16, zL6, 256);
    ab_kernel<<<1, blk, 0, stream>>>(st + stOff[5], g[5], bt[5], ab + abOff[5], 256, 1.0 / 256);

    // ---- final BN+ReLU6 -> out
    apply_kernel<<<(65536 + 255) / 256, blk, 0, stream>>>(bufB, ab + abOff[5], (float*)d_out,
                                                          65536, 256, 16);
}